// Round 5
// baseline (1049.208 us; speedup 1.0000x reference)
//
#include <hip/hip_runtime.h>

// RegressorHybrid: per-edge 2x MLP (128->64->64->32->1, lrelu 0.01), E=2M, H=64.
// Round 5: lane-private-line gathers. Measured R1-R4: same-line requests from
// multiple lanes WITHIN one VMEM instruction each trigger their own 64B fill
// (4x FETCH); cross-instruction re-touches merge via L1/MSHR (R1 clean).
// So each of the 4 gather loads is a bijection lane->line: load j, lane (q,n)
// reads chunk q of edge n's line for combo (q+j)&3 (combo: src-h0/src-h1/
// dst-h0/dst-h1). A 2-step masked rotate (rotate-right by q, 32 cndmask)
// reorders regs into B1 fragments. No bpermute, no sorting, prefetch depth 1.
// MFMA layouts: A[m=lane&15][k=(lane>>4)*8+j], B[k=(lane>>4)*8+j][n=lane&15],
//               C/D[row=4*(lane>>4)+reg][col=lane&15].

typedef _Float16 half8  __attribute__((ext_vector_type(8)));
typedef _Float16 half4v __attribute__((ext_vector_type(4)));
typedef float    float4v __attribute__((ext_vector_type(4)));

#define LDS_PER_MLP 28672          // w1f 16384 + w2f 8192 + w3f 4096
#define LDS_TOTAL   57344
#define REST_PER_MLP 12288         // w4f 2048 + b1f 4096 + b2f 4096 + b3f 2048
#define W1F 0
#define W2F 16384
#define W3F 24576
#define RW4F 0
#define RB1F 2048
#define RB2F 6144
#define RB3F 10240
#define WS_REST_OFF 57344
#define WS_X16_OFF  81920

__device__ __forceinline__ float lrelu(float x) { return fmaxf(x, 0.01f * x); }

__device__ __forceinline__ int uperm(int k) {
    return 16 * (2 * ((k >> 2) & 1) + ((k >> 5) & 1)) + 4 * ((k >> 3) & 3) + (k & 3);
}

// ---- pack one MLP's weights/biases into per-lane fragment order ----
__global__ void prep_frags(const float* __restrict__ w1, const float* __restrict__ b1,
                           const float* __restrict__ w2, const float* __restrict__ b2,
                           const float* __restrict__ w3, const float* __restrict__ b3,
                           const float* __restrict__ w4,
                           unsigned char* __restrict__ dstL,
                           unsigned char* __restrict__ dstR)
{
    int idx = blockIdx.x * blockDim.x + threadIdx.x;
    if (idx < 8192) {                      // w1f: [16 frags][64 lanes][8 f16]
        int L = (idx >> 3) & 63, j = idx & 7, f = idx >> 9;
        int q = L >> 4, mm = L & 15, t = f >> 2, s = f & 3;
        int k = 32 * s + 8 * q + j;
        ((_Float16*)(dstL + W1F))[idx] = (_Float16)w1[k * 64 + 16 * t + mm];
        return;
    }
    idx -= 8192;
    if (idx < 4096) {                      // w2f: [8][64][8]
        int L = (idx >> 3) & 63, j = idx & 7, f = idx >> 9;
        int q = L >> 4, mm = L & 15, t = f >> 1, s = f & 1;
        int u = uperm(32 * s + 8 * q + j);
        ((_Float16*)(dstL + W2F))[idx] = (_Float16)w2[u * 64 + 16 * t + mm];
        return;
    }
    idx -= 4096;
    if (idx < 2048) {                      // w3f: [4][64][8]
        int L = (idx >> 3) & 63, j = idx & 7, f = idx >> 9;
        int q = L >> 4, mm = L & 15, t = f >> 1, s = f & 1;
        int u = uperm(32 * s + 8 * q + j);
        ((_Float16*)(dstL + W3F))[idx] = (_Float16)w3[u * 32 + 16 * t + mm];
        return;
    }
    idx -= 2048;
    if (idx < 512) {                       // w4f
        int L = idx >> 3, j = idx & 7;
        int q = L >> 4, t = j >> 2, r = j & 3;
        ((float*)(dstR + RW4F))[idx] = w4[16 * t + 4 * q + r];
        return;
    }
    idx -= 512;
    if (idx < 1024) {                      // b1f
        int t = idx >> 8, L = (idx >> 2) & 63, r = idx & 3, q = L >> 4;
        ((float*)(dstR + RB1F))[idx] = b1[16 * t + 4 * q + r];
        return;
    }
    idx -= 1024;
    if (idx < 1024) {                      // b2f
        int t = idx >> 8, L = (idx >> 2) & 63, r = idx & 3, q = L >> 4;
        ((float*)(dstR + RB2F))[idx] = b2[16 * t + 4 * q + r];
        return;
    }
    idx -= 1024;
    if (idx < 512) {                       // b3f
        int t = idx >> 8, L = (idx >> 2) & 63, r = idx & 3, q = L >> 4;
        ((float*)(dstR + RB3F))[idx] = b3[16 * t + 4 * q + r];
        return;
    }
}

// ---- convert node tables fp32 -> f16 ----
__global__ void prep_nodes(const float* __restrict__ xs, const float* __restrict__ xd,
                           _Float16* __restrict__ os, _Float16* __restrict__ od, int n4)
{
    int stride = gridDim.x * blockDim.x;
    for (int i = blockIdx.x * blockDim.x + threadIdx.x; i < n4; i += stride) {
        float4v a = ((const float4v*)xs)[i];
        float4v b = ((const float4v*)xd)[i];
        half4v ha, hb;
#pragma unroll
        for (int j = 0; j < 4; ++j) { ha[j] = (_Float16)a[j]; hb[j] = (_Float16)b[j]; }
        ((half4v*)os)[i] = ha;
        ((half4v*)od)[i] = hb;
    }
}

__device__ __forceinline__ half8 repack2(float4v lo, float4v hi) {
    half8 r;
#pragma unroll
    for (int j = 0; j < 4; ++j) r[j] = (_Float16)lrelu(lo[j]);
#pragma unroll
    for (int j = 0; j < 4; ++j) r[4 + j] = (_Float16)lrelu(hi[j]);
    return r;
}

// lane-private-line gather: load j reads chunk q of combo (q+j)&3 for edge n.
// Every load instruction touches 64 DISTINCT 64B lines (bijection lane->line).
__device__ __forceinline__ void gather_tile(const _Float16* __restrict__ xs,
                                            const _Float16* __restrict__ xd,
                                            const int* __restrict__ eidx,
                                            int nE, int tile, int q, int n, int4* G)
{
    int e = tile * 16 + n;
    int ec = e < nE ? e : nE - 1;
    int si = eidx[ec];
    int di = eidx[nE + ec];
    const char* rs = (const char*)(xs + (size_t)si * 64);
    const char* rd = (const char*)(xd + (size_t)di * 64);
#pragma unroll
    for (int j = 0; j < 4; ++j) {
        int combo = (q + j) & 3;
        const char* base = (combo & 2) ? rd : rs;
        G[j] = *(const int4*)(base + (combo & 1) * 64 + 16 * q);
    }
}

// reorder G (combo (q+j)&3 in reg j) into B (combo c in reg c): rotate-right by q
__device__ __forceinline__ void rotate_to_frags(const int4* G, int q, half8* B1)
{
    bool r1 = (q & 1) != 0, r2 = (q & 2) != 0;
    int4 T[4], Bv[4];
#pragma unroll
    for (int c = 0; c < 4; ++c) T[c] = r1 ? G[(c + 3) & 3] : G[c];
#pragma unroll
    for (int c = 0; c < 4; ++c) Bv[c] = r2 ? T[(c + 2) & 3] : T[c];
#pragma unroll
    for (int c = 0; c < 4; ++c) B1[c] = __builtin_bit_cast(half8, Bv[c]);
}

__global__ __launch_bounds__(256, 2)
void edge_mlp_mfma(const unsigned char* __restrict__ ws,
                   const _Float16* __restrict__ xs, const _Float16* __restrict__ xd,
                   const int* __restrict__ eidx,
                   const float* __restrict__ eb4p, const float* __restrict__ wb4p,
                   float* __restrict__ out, int nE, int ntiles)
{
    __shared__ unsigned char lds[LDS_TOTAL];
    {
        const uint4* s = (const uint4*)ws;
        uint4* d = (uint4*)lds;
        for (int i = threadIdx.x; i < LDS_TOTAL / 16; i += 256) d[i] = s[i];
    }
    __syncthreads();

    const int lane = threadIdx.x & 63;
    const int q = lane >> 4, n = lane & 15;
    const int wid = (blockIdx.x << 2) | (threadIdx.x >> 6);
    const int nwaves = gridDim.x << 2;

    // hoist bias / w4 fragments
    float4v b1v[2][4], b2v[2][4], b3v[2][2], w4v[2][2];
    float b4s[2];
    const float* b4p[2] = { eb4p, wb4p };
#pragma unroll
    for (int m = 0; m < 2; ++m) {
        const unsigned char* rb = ws + WS_REST_OFF + m * REST_PER_MLP;
#pragma unroll
        for (int t = 0; t < 4; ++t) b1v[m][t] = *(const float4v*)(rb + RB1F + (t * 64 + lane) * 16);
#pragma unroll
        for (int t = 0; t < 4; ++t) b2v[m][t] = *(const float4v*)(rb + RB2F + (t * 64 + lane) * 16);
#pragma unroll
        for (int t = 0; t < 2; ++t) b3v[m][t] = *(const float4v*)(rb + RB3F + (t * 64 + lane) * 16);
        w4v[m][0] = *(const float4v*)(rb + RW4F + lane * 32);
        w4v[m][1] = *(const float4v*)(rb + RW4F + lane * 32 + 16);
        b4s[m] = b4p[m][0];
    }

    int4 Gcur[4], Gnxt[4];
    int tile = wid;
    if (tile < ntiles)
        gather_tile(xs, xd, eidx, nE, tile, q, n, Gcur);

#pragma unroll 1
    for (; tile < ntiles; tile += nwaves) {
        // reorder current tile's regs into B1 fragments (waits vmcnt on Gcur)
        half8 B1[4];
        rotate_to_frags(Gcur, q, B1);

        // prefetch next tile (overlaps with compute below)
        int tn = tile + nwaves;
        if (tn < ntiles)
            gather_tile(xs, xd, eidx, nE, tn, q, n, Gnxt);

        float res[2];
#pragma unroll
        for (int m = 0; m < 2; ++m) {
            const unsigned char* mb = lds + m * LDS_PER_MLP;
            // ---- layer 1: 128 -> 64 ----
            float4v acc[4];
#pragma unroll
            for (int t = 0; t < 4; ++t) {
                acc[t] = b1v[m][t];
#pragma unroll
                for (int s = 0; s < 4; ++s) {
                    half8 A = *(const half8*)(mb + W1F + ((t * 4 + s) * 64 + lane) * 16);
                    acc[t] = __builtin_amdgcn_mfma_f32_16x16x32_f16(A, B1[s], acc[t], 0, 0, 0);
                }
            }
            // ---- layer 2: 64 -> 64 ----
            half8 B2[2] = { repack2(acc[0], acc[2]), repack2(acc[1], acc[3]) };
            float4v acc2[4];
#pragma unroll
            for (int t = 0; t < 4; ++t) {
                acc2[t] = b2v[m][t];
#pragma unroll
                for (int s = 0; s < 2; ++s) {
                    half8 A = *(const half8*)(mb + W2F + ((t * 2 + s) * 64 + lane) * 16);
                    acc2[t] = __builtin_amdgcn_mfma_f32_16x16x32_f16(A, B2[s], acc2[t], 0, 0, 0);
                }
            }
            // ---- layer 3: 64 -> 32 ----
            half8 B3[2] = { repack2(acc2[0], acc2[2]), repack2(acc2[1], acc2[3]) };
            float4v acc3[2];
#pragma unroll
            for (int t = 0; t < 2; ++t) {
                acc3[t] = b3v[m][t];
#pragma unroll
                for (int s = 0; s < 2; ++s) {
                    half8 A = *(const half8*)(mb + W3F + ((t * 2 + s) * 64 + lane) * 16);
                    acc3[t] = __builtin_amdgcn_mfma_f32_16x16x32_f16(A, B3[s], acc3[t], 0, 0, 0);
                }
            }
            // ---- layer 4: 32 -> 1 ----
            float o = 0.f;
#pragma unroll
            for (int r = 0; r < 4; ++r) o = fmaf(lrelu(acc3[0][r]), w4v[m][0][r], o);
#pragma unroll
            for (int r = 0; r < 4; ++r) o = fmaf(lrelu(acc3[1][r]), w4v[m][1][r], o);
            o += __shfl_xor(o, 16, 64);
            o += __shfl_xor(o, 32, 64);
            res[m] = o + b4s[m];
        }
        int e = tile * 16 + n;
        if (q == 0 && e < nE) {
            out[e] = res[0];
            out[nE + e] = res[1];
        }
#pragma unroll
        for (int s = 0; s < 4; ++s) Gcur[s] = Gnxt[s];
    }
}

extern "C" void kernel_launch(void* const* d_in, const int* in_sizes, int n_in,
                              void* d_out, int out_size, void* d_ws, size_t ws_size,
                              hipStream_t stream)
{
    const float* x_src = (const float*)d_in[0];
    const float* x_dst = (const float*)d_in[1];
    const int*   eidx  = (const int*)d_in[2];
    const float* ew1 = (const float*)d_in[3];
    const float* eb1 = (const float*)d_in[4];
    const float* ww1 = (const float*)d_in[5];
    const float* wb1 = (const float*)d_in[6];
    const float* ew2 = (const float*)d_in[7];
    const float* eb2 = (const float*)d_in[8];
    const float* ww2 = (const float*)d_in[9];
    const float* wb2 = (const float*)d_in[10];
    const float* ew3 = (const float*)d_in[11];
    const float* eb3 = (const float*)d_in[12];
    const float* ww3 = (const float*)d_in[13];
    const float* wb3 = (const float*)d_in[14];
    const float* ew4 = (const float*)d_in[15];
    const float* eb4 = (const float*)d_in[16];
    const float* ww4 = (const float*)d_in[17];
    const float* wb4 = (const float*)d_in[18];
    float* out = (float*)d_out;

    const int nE = in_sizes[2] / 2;          // 2 x E index array (int32)
    const int nNodeElems = in_sizes[0];      // N_NODES * 64
    unsigned char* ws = (unsigned char*)d_ws;
    _Float16* xs16 = (_Float16*)(ws + WS_X16_OFF);
    _Float16* xd16 = xs16 + nNodeElems;

    prep_frags<<<68, 256, 0, stream>>>(ew1, eb1, ew2, eb2, ew3, eb3, ew4,
                                       ws, ws + WS_REST_OFF);
    prep_frags<<<68, 256, 0, stream>>>(ww1, wb1, ww2, wb2, ww3, wb3, ww4,
                                       ws + LDS_PER_MLP, ws + WS_REST_OFF + REST_PER_MLP);
    prep_nodes<<<1024, 256, 0, stream>>>(x_src, x_dst, xs16, xd16, nNodeElems / 4);

    const int ntiles = (nE + 15) / 16;
    edge_mlp_mfma<<<512, 256, 0, stream>>>(ws, xs16, xd16, eidx, eb4, wb4,
                                           out, nE, ntiles);
}

// Round 6
// 380.823 us; speedup vs baseline: 2.7551x; 2.7551x over previous
//
#include <hip/hip_runtime.h>

// RegressorHybrid: per-edge 2x MLP (128->64->64->32->1, lrelu 0.01), E=2M, H=64.
// Round 6: warm-pass gathers. Measured law (R1-R5): each MISSING b128 lane-
// request = its own 64B fill (no merge across lanes/in-flight reqs; R2 FETCH
// = rows*4 + eidx exactly); temporally-separated re-touches HIT L1 (R1);
// dword requests coalesce (eidx clean). Fix: one warm b128 instr per tile
// (64 lanes -> the tile's 64 distinct lines, 1 fill each = raw bytes), issued
// 3 iterations ahead; R2-style consume gather then hits L1/L2 (hits don't
// fill). Warm results folded into junk (xor, 2-iter-old => no stall), consumed
// by a never-taken guard. Bias/w4 frags re-loaded per tile from a fixed 24KB
// L1-resident region instead of 96 persistent VGPRs; __launch_bounds__(256,4)
// pins the 128-VGPR / 2-blocks-per-CU point. No dynamic-indexed arrays
// (R5's rotate demoted to LDS/scratch: +16KB LDS, 1GB scratch writes).
// MFMA layouts: A[m=lane&15][k=(lane>>4)*8+j], B[k=(lane>>4)*8+j][n=lane&15],
//               C/D[row=4*(lane>>4)+reg][col=lane&15].

typedef _Float16 half8  __attribute__((ext_vector_type(8)));
typedef _Float16 half4v __attribute__((ext_vector_type(4)));
typedef float    float4v __attribute__((ext_vector_type(4)));

#define LDS_PER_MLP 28672          // w1f 16384 + w2f 8192 + w3f 4096
#define LDS_TOTAL   57344
#define REST_PER_MLP 12288         // w4f 2048 + b1f 4096 + b2f 4096 + b3f 2048
#define W1F 0
#define W2F 16384
#define W3F 24576
#define RW4F 0
#define RB1F 2048
#define RB2F 6144
#define RB3F 10240
#define WS_REST_OFF 57344
#define WS_X16_OFF  81920

__device__ __forceinline__ float lrelu(float x) { return fmaxf(x, 0.01f * x); }

__device__ __forceinline__ int uperm(int k) {
    return 16 * (2 * ((k >> 2) & 1) + ((k >> 5) & 1)) + 4 * ((k >> 3) & 3) + (k & 3);
}

// ---- pack one MLP's weights/biases into per-lane fragment order ----
__global__ void prep_frags(const float* __restrict__ w1, const float* __restrict__ b1,
                           const float* __restrict__ w2, const float* __restrict__ b2,
                           const float* __restrict__ w3, const float* __restrict__ b3,
                           const float* __restrict__ w4,
                           unsigned char* __restrict__ dstL,
                           unsigned char* __restrict__ dstR)
{
    int idx = blockIdx.x * blockDim.x + threadIdx.x;
    if (idx < 8192) {                      // w1f: [16 frags][64 lanes][8 f16]
        int L = (idx >> 3) & 63, j = idx & 7, f = idx >> 9;
        int q = L >> 4, mm = L & 15, t = f >> 2, s = f & 3;
        int k = 32 * s + 8 * q + j;
        ((_Float16*)(dstL + W1F))[idx] = (_Float16)w1[k * 64 + 16 * t + mm];
        return;
    }
    idx -= 8192;
    if (idx < 4096) {                      // w2f: [8][64][8]
        int L = (idx >> 3) & 63, j = idx & 7, f = idx >> 9;
        int q = L >> 4, mm = L & 15, t = f >> 1, s = f & 1;
        int u = uperm(32 * s + 8 * q + j);
        ((_Float16*)(dstL + W2F))[idx] = (_Float16)w2[u * 64 + 16 * t + mm];
        return;
    }
    idx -= 4096;
    if (idx < 2048) {                      // w3f: [4][64][8]
        int L = (idx >> 3) & 63, j = idx & 7, f = idx >> 9;
        int q = L >> 4, mm = L & 15, t = f >> 1, s = f & 1;
        int u = uperm(32 * s + 8 * q + j);
        ((_Float16*)(dstL + W3F))[idx] = (_Float16)w3[u * 32 + 16 * t + mm];
        return;
    }
    idx -= 2048;
    if (idx < 512) {                       // w4f
        int L = idx >> 3, j = idx & 7;
        int q = L >> 4, t = j >> 2, r = j & 3;
        ((float*)(dstR + RW4F))[idx] = w4[16 * t + 4 * q + r];
        return;
    }
    idx -= 512;
    if (idx < 1024) {                      // b1f
        int t = idx >> 8, L = (idx >> 2) & 63, r = idx & 3, q = L >> 4;
        ((float*)(dstR + RB1F))[idx] = b1[16 * t + 4 * q + r];
        return;
    }
    idx -= 1024;
    if (idx < 1024) {                      // b2f
        int t = idx >> 8, L = (idx >> 2) & 63, r = idx & 3, q = L >> 4;
        ((float*)(dstR + RB2F))[idx] = b2[16 * t + 4 * q + r];
        return;
    }
    idx -= 1024;
    if (idx < 512) {                       // b3f
        int t = idx >> 8, L = (idx >> 2) & 63, r = idx & 3, q = L >> 4;
        ((float*)(dstR + RB3F))[idx] = b3[16 * t + 4 * q + r];
        return;
    }
}

// ---- convert node tables fp32 -> f16 ----
__global__ void prep_nodes(const float* __restrict__ xs, const float* __restrict__ xd,
                           _Float16* __restrict__ os, _Float16* __restrict__ od, int n4)
{
    int stride = gridDim.x * blockDim.x;
    for (int i = blockIdx.x * blockDim.x + threadIdx.x; i < n4; i += stride) {
        float4v a = ((const float4v*)xs)[i];
        float4v b = ((const float4v*)xd)[i];
        half4v ha, hb;
#pragma unroll
        for (int j = 0; j < 4; ++j) { ha[j] = (_Float16)a[j]; hb[j] = (_Float16)b[j]; }
        ((half4v*)os)[i] = ha;
        ((half4v*)od)[i] = hb;
    }
}

__device__ __forceinline__ half8 repack2(float4v lo, float4v hi) {
    half8 r;
#pragma unroll
    for (int j = 0; j < 4; ++j) r[j] = (_Float16)lrelu(lo[j]);
#pragma unroll
    for (int j = 0; j < 4; ++j) r[4 + j] = (_Float16)lrelu(hi[j]);
    return r;
}

// R2-style consume gather: lane (q,n) loads chunk q of edge n's 4 lines.
// These requests HIT L1/L2 (warmed 3 iterations earlier) -> no fills.
__device__ __forceinline__ void gather_tile(const _Float16* __restrict__ xs,
                                            const _Float16* __restrict__ xd,
                                            const int* __restrict__ eidx,
                                            int nE, int tile, int q, int n, int4* G)
{
    int e = tile * 16 + n;
    int ec = e < nE ? e : nE - 1;
    int si = eidx[ec];
    int di = eidx[nE + ec];
    const char* rs = (const char*)(xs + (size_t)si * 64);
    const char* rd = (const char*)(xd + (size_t)di * 64);
    G[0] = *(const int4*)(rs + 16 * q);
    G[1] = *(const int4*)(rs + 64 + 16 * q);
    G[2] = *(const int4*)(rd + 16 * q);
    G[3] = *(const int4*)(rd + 64 + 16 * q);
}

// warm pass: lane (c=q, n) touches line (edge n, combo c) once -> 64 distinct
// lines per instruction, exactly one 64B fill each.
__device__ __forceinline__ int4 warm_tile(const _Float16* __restrict__ xs,
                                          const _Float16* __restrict__ xd,
                                          const int* __restrict__ eidx,
                                          int nE, int tile, int c, int n)
{
    int e = tile * 16 + n;
    int ec = e < nE ? e : nE - 1;
    int idx = (c & 2) ? eidx[nE + ec] : eidx[ec];
    const char* base = (const char*)(((c & 2) ? xd : xs) + (size_t)idx * 64);
    return *(const int4*)(base + (c & 1) * 64);
}

__global__ __launch_bounds__(256, 4)
void edge_mlp_mfma(const unsigned char* __restrict__ ws,
                   const _Float16* __restrict__ xs, const _Float16* __restrict__ xd,
                   const int* __restrict__ eidx,
                   const float* __restrict__ eb4p, const float* __restrict__ wb4p,
                   float* __restrict__ out, int nE, int ntiles)
{
    __shared__ unsigned char lds[LDS_TOTAL];
    {
        const uint4* s = (const uint4*)ws;
        uint4* d = (uint4*)lds;
        for (int i = threadIdx.x; i < LDS_TOTAL / 16; i += 256) d[i] = s[i];
    }
    __syncthreads();

    const int lane = threadIdx.x & 63;
    const int q = lane >> 4, n = lane & 15;
    const int wid = (blockIdx.x << 2) | (threadIdx.x >> 6);
    const int nwaves = gridDim.x << 2;
    const float b4s0 = eb4p[0], b4s1 = wb4p[0];
    const unsigned char* rbias = ws + WS_REST_OFF;

    int4 Gcur[4], Gnxt[4];
    int4 W0 = {0,0,0,0}, W1 = {0,0,0,0}, W2 = {0,0,0,0}, junk = {0,0,0,0};

    int tile = wid;
    if (tile < ntiles) {
        int t1 = tile + nwaves;     if (t1 >= ntiles) t1 = ntiles - 1;
        int t2 = tile + 2 * nwaves; if (t2 >= ntiles) t2 = ntiles - 1;
        W0 = warm_tile(xs, xd, eidx, nE, tile, q, n);
        W1 = warm_tile(xs, xd, eidx, nE, t1, q, n);
        W2 = warm_tile(xs, xd, eidx, nE, t2, q, n);
        gather_tile(xs, xd, eidx, nE, tile, q, n, Gcur);
    }

#pragma unroll 1
    for (; tile < ntiles; tile += nwaves) {
        half8 B1[4];
#pragma unroll
        for (int s = 0; s < 4; ++s) B1[s] = __builtin_bit_cast(half8, Gcur[s]);

        // prefetch next tile's consume gather (hits warmed lines)
        int tn = tile + nwaves;
        if (tn < ntiles)
            gather_tile(xs, xd, eidx, nE, tn, q, n, Gnxt);

        // fold oldest warm (2 iters old -> complete), rotate, issue new warm
        junk.x ^= W0.x; junk.y ^= W0.y; junk.z ^= W0.z; junk.w ^= W0.w;
        W0 = W1; W1 = W2;
        {
            int tw = tile + 3 * nwaves;
            if (tw >= ntiles) tw = ntiles - 1;
            W2 = warm_tile(xs, xd, eidx, nE, tw, q, n);
        }

        float res0, res1;
#pragma unroll
        for (int m = 0; m < 2; ++m) {
            const unsigned char* mb = lds + m * LDS_PER_MLP;
            const unsigned char* rb = rbias + m * REST_PER_MLP;
            // ---- layer 1: 128 -> 64 (bias via C-init, per-tile L1-hit loads) ----
            float4v acc[4];
#pragma unroll
            for (int t = 0; t < 4; ++t) {
                acc[t] = *(const float4v*)(rb + RB1F + (t * 64 + lane) * 16);
#pragma unroll
                for (int s = 0; s < 4; ++s) {
                    half8 A = *(const half8*)(mb + W1F + ((t * 4 + s) * 64 + lane) * 16);
                    acc[t] = __builtin_amdgcn_mfma_f32_16x16x32_f16(A, B1[s], acc[t], 0, 0, 0);
                }
            }
            // ---- layer 2: 64 -> 64 ----
            half8 B2[2] = { repack2(acc[0], acc[2]), repack2(acc[1], acc[3]) };
            float4v acc2[4];
#pragma unroll
            for (int t = 0; t < 4; ++t) {
                acc2[t] = *(const float4v*)(rb + RB2F + (t * 64 + lane) * 16);
#pragma unroll
                for (int s = 0; s < 2; ++s) {
                    half8 A = *(const half8*)(mb + W2F + ((t * 2 + s) * 64 + lane) * 16);
                    acc2[t] = __builtin_amdgcn_mfma_f32_16x16x32_f16(A, B2[s], acc2[t], 0, 0, 0);
                }
            }
            // ---- layer 3: 64 -> 32 ----
            half8 B3[2] = { repack2(acc2[0], acc2[2]), repack2(acc2[1], acc2[3]) };
            float4v acc3[2];
#pragma unroll
            for (int t = 0; t < 2; ++t) {
                acc3[t] = *(const float4v*)(rb + RB3F + (t * 64 + lane) * 16);
#pragma unroll
                for (int s = 0; s < 2; ++s) {
                    half8 A = *(const half8*)(mb + W3F + ((t * 2 + s) * 64 + lane) * 16);
                    acc3[t] = __builtin_amdgcn_mfma_f32_16x16x32_f16(A, B3[s], acc3[t], 0, 0, 0);
                }
            }
            // ---- layer 4: 32 -> 1 ----
            float4v w40 = *(const float4v*)(rb + RW4F + lane * 32);
            float4v w41 = *(const float4v*)(rb + RW4F + lane * 32 + 16);
            float o = 0.f;
#pragma unroll
            for (int r = 0; r < 4; ++r) o = fmaf(lrelu(acc3[0][r]), w40[r], o);
#pragma unroll
            for (int r = 0; r < 4; ++r) o = fmaf(lrelu(acc3[1][r]), w41[r], o);
            o += __shfl_xor(o, 16, 64);
            o += __shfl_xor(o, 32, 64);
            if (m == 0) res0 = o + b4s0; else res1 = o + b4s1;
        }
        int e = tile * 16 + n;
        if (q == 0 && e < nE) {
            out[e] = res0;
            out[nE + e] = res1;
        }
#pragma unroll
        for (int s = 0; s < 4; ++s) Gcur[s] = Gnxt[s];
    }

    // consume warm registers (never-taken, data-dependent guard defeats DCE)
    junk.x ^= W0.x ^ W1.x ^ W2.x;
    junk.y ^= W0.y ^ W1.y ^ W2.y;
    junk.z ^= W0.z ^ W1.z ^ W2.z;
    junk.w ^= W0.w ^ W1.w ^ W2.w;
    if (nE < 0 && (junk.x | junk.y | junk.z | junk.w) != 0)
        out[0] = -1.0f;
}

extern "C" void kernel_launch(void* const* d_in, const int* in_sizes, int n_in,
                              void* d_out, int out_size, void* d_ws, size_t ws_size,
                              hipStream_t stream)
{
    const float* x_src = (const float*)d_in[0];
    const float* x_dst = (const float*)d_in[1];
    const int*   eidx  = (const int*)d_in[2];
    const float* ew1 = (const float*)d_in[3];
    const float* eb1 = (const float*)d_in[4];
    const float* ww1 = (const float*)d_in[5];
    const float* wb1 = (const float*)d_in[6];
    const float* ew2 = (const float*)d_in[7];
    const float* eb2 = (const float*)d_in[8];
    const float* ww2 = (const float*)d_in[9];
    const float* wb2 = (const float*)d_in[10];
    const float* ew3 = (const float*)d_in[11];
    const float* eb3 = (const float*)d_in[12];
    const float* ww3 = (const float*)d_in[13];
    const float* wb3 = (const float*)d_in[14];
    const float* ew4 = (const float*)d_in[15];
    const float* eb4 = (const float*)d_in[16];
    const float* ww4 = (const float*)d_in[17];
    const float* wb4 = (const float*)d_in[18];
    float* out = (float*)d_out;

    const int nE = in_sizes[2] / 2;          // 2 x E index array (int32)
    const int nNodeElems = in_sizes[0];      // N_NODES * 64
    unsigned char* ws = (unsigned char*)d_ws;
    _Float16* xs16 = (_Float16*)(ws + WS_X16_OFF);
    _Float16* xd16 = xs16 + nNodeElems;

    prep_frags<<<68, 256, 0, stream>>>(ew1, eb1, ew2, eb2, ew3, eb3, ew4,
                                       ws, ws + WS_REST_OFF);
    prep_frags<<<68, 256, 0, stream>>>(ww1, wb1, ww2, wb2, ww3, wb3, ww4,
                                       ws + LDS_PER_MLP, ws + WS_REST_OFF + REST_PER_MLP);
    prep_nodes<<<1024, 256, 0, stream>>>(x_src, x_dst, xs16, xd16, nNodeElems / 4);

    const int ntiles = (nE + 15) / 16;
    edge_mlp_mfma<<<512, 256, 0, stream>>>(ws, xs16, xd16, eidx, eb4, wb4,
                                           out, nE, ntiles);
}